// Round 3
// baseline (3316.884 us; speedup 1.0000x reference)
//
#include <hip/hip_runtime.h>
#include <math.h>

#define Bn 8
#define Vn 5000
#define Cn 256
#define Kn 200

// workspace layout (floats):
//   AB   [16][200][256] @ 0         (mats 0..7 = A per batch, 8..15 = Bc)
//   AAT  [16][200][200] @ 819200    (mats 0..7 = A·Aᵀ, 8..15 = B·Aᵀ)
//   PART [16][16][200][256] @ 1459456 (split-K partials, if ws is big enough)
#define AB_OFF   0
#define AAT_OFF  819200
#define PART_OFF 1459456
#define WS_NEED_FLOATS (PART_OFF + (size_t)16 * 16 * Kn * Cn)

// ---------------------------------------------------------------------------
// K1: A[b] = evecs_trans_x[b] (200x5000) @ feat_x[b] (5000x256), same for y.
// Tile 64x128, 128 threads, 8x8 micro: 4 ds_read_b128 per 64 FMAs.
// Split-K=16 (2048 blocks -> 8 blocks/CU = 4 waves/SIMD; R2's split-8 gave
// only 2 waves/SIMD, latency-exposed). Partials + reduce (no atomics).
// ---------------------------------------------------------------------------
template<int USE_ATOMIC>
__global__ __launch_bounds__(128, 4) void k_gemm_ab(
    const float* __restrict__ fx, const float* __restrict__ fy,
    const float* __restrict__ etx, const float* __restrict__ ety,
    float* __restrict__ AB, float* __restrict__ part)
{
    __shared__ float EsT[16 * 72];    // [kk][row]
    __shared__ float Fs[16 * 132];    // [kk][col]
    const int bid = blockIdx.x;       // 16 mats * 4 tr * 2 tc * 16 ks = 2048
    const int ks  = bid & 15;
    const int t   = bid >> 4;         // mat*8 + tr*2 + tc
    const int tc  = t & 1;
    const int tr  = (t >> 1) & 3;
    const int mat = t >> 3;
    const int b = mat & 7, which = mat >> 3;
    const float* __restrict__ E = (which ? ety : etx) + (size_t)b * Kn * Vn;
    const float* __restrict__ F = (which ? fy : fx) + (size_t)b * Vn * Cn;
    const int row0 = tr * 64, col0 = tc * 128;
    const int kstart = ks * 320;
    const int kend = (kstart + 320 < Vn) ? (kstart + 320) : Vn;
    const int tid = threadIdx.x;
    const int tx = tid & 15, ty = tid >> 4;   // cols 16x8, rows 8x8
    float4 acc[8][2] = {};

    for (int k0 = kstart; k0 < kend; k0 += 16) {
#pragma unroll
        for (int i = 0; i < 2; ++i) {
            int idx = tid + i * 128;          // 256 float4s
            int r = idx >> 2, k4 = idx & 3;
            int gr = row0 + r, gk = k0 + k4 * 4;
            float4 v = make_float4(0.f, 0.f, 0.f, 0.f);
            if (gr < Kn && gk < kend) v = *(const float4*)&E[(size_t)gr * Vn + gk];
            EsT[(k4 * 4 + 0) * 72 + r] = v.x;
            EsT[(k4 * 4 + 1) * 72 + r] = v.y;
            EsT[(k4 * 4 + 2) * 72 + r] = v.z;
            EsT[(k4 * 4 + 3) * 72 + r] = v.w;
        }
#pragma unroll
        for (int i = 0; i < 4; ++i) {
            int idx = tid + i * 128;          // 512 float4s
            int c4 = idx & 31, rv = idx >> 5;
            int gv = k0 + rv;
            float4 v = make_float4(0.f, 0.f, 0.f, 0.f);
            if (gv < kend) v = *(const float4*)&F[(size_t)gv * Cn + col0 + c4 * 4];
            *(float4*)&Fs[rv * 132 + c4 * 4] = v;
        }
        __syncthreads();
#pragma unroll
        for (int kk = 0; kk < 16; ++kk) {
            float4 a0 = *(const float4*)&EsT[kk * 72 + ty * 8];
            float4 a1 = *(const float4*)&EsT[kk * 72 + ty * 8 + 4];
            float4 b0 = *(const float4*)&Fs[kk * 132 + tx * 8];
            float4 b1 = *(const float4*)&Fs[kk * 132 + tx * 8 + 4];
            float av[8] = {a0.x, a0.y, a0.z, a0.w, a1.x, a1.y, a1.z, a1.w};
#pragma unroll
            for (int m = 0; m < 8; ++m) {
                acc[m][0].x += av[m] * b0.x; acc[m][0].y += av[m] * b0.y;
                acc[m][0].z += av[m] * b0.z; acc[m][0].w += av[m] * b0.w;
                acc[m][1].x += av[m] * b1.x; acc[m][1].y += av[m] * b1.y;
                acc[m][1].z += av[m] * b1.z; acc[m][1].w += av[m] * b1.w;
            }
        }
        __syncthreads();
    }

#pragma unroll
    for (int m = 0; m < 8; ++m) {
        int gr = row0 + ty * 8 + m;
        if (gr < Kn) {
            if (USE_ATOMIC) {
                float* o = AB + ((size_t)mat * Kn + gr) * Cn + col0 + tx * 8;
                atomicAdd(&o[0], acc[m][0].x); atomicAdd(&o[1], acc[m][0].y);
                atomicAdd(&o[2], acc[m][0].z); atomicAdd(&o[3], acc[m][0].w);
                atomicAdd(&o[4], acc[m][1].x); atomicAdd(&o[5], acc[m][1].y);
                atomicAdd(&o[6], acc[m][1].z); atomicAdd(&o[7], acc[m][1].w);
            } else {
                float* o = part + (((size_t)(ks * 16 + mat) * Kn + gr) * Cn) + col0 + tx * 8;
                *(float4*)&o[0] = acc[m][0];
                *(float4*)&o[4] = acc[m][1];
            }
        }
    }
}

// ---------------------------------------------------------------------------
// K1b: AB = sum over 16 split-K partials. ~55 MB traffic, ~10us.
// ---------------------------------------------------------------------------
__global__ __launch_bounds__(512) void k_reduce(
    const float4* __restrict__ part, float4* __restrict__ AB)
{
    const int i = blockIdx.x * 512 + threadIdx.x;   // 204800 float4s, grid 400
    float4 s = part[i];
#pragma unroll
    for (int sp = 1; sp < 16; ++sp) {
        float4 v = part[(size_t)sp * 204800 + i];
        s.x += v.x; s.y += v.y; s.z += v.z; s.w += v.w;
    }
    AB[i] = s;
}

// ---------------------------------------------------------------------------
// K2: AAT[m] = X[m] (200x256) @ A2ᵀ (256x200), X = A (m<8) or Bc (m>=8).
// ---------------------------------------------------------------------------
__global__ __launch_bounds__(256) void k_gemm_nt(
    const float* __restrict__ AB, float* __restrict__ AAT)
{
    __shared__ float Xs[64 * 33];
    __shared__ float As[64 * 33];
    const int bid = blockIdx.x;
    const int mat = bid >> 4;
    const int tile = bid & 15;
    const int tr = tile >> 2, tc = tile & 3;
    const float* __restrict__ X  = AB + mat * Kn * Cn;
    const float* __restrict__ A2 = AB + (mat & 7) * Kn * Cn;
    float* __restrict__ out = AAT + mat * Kn * Kn;
    const int r0 = tr * 64, j0 = tc * 64;
    const int tid = threadIdx.x;
    const int tx = tid & 15, ty = tid >> 4;
    float acc[4][4] = {};

    for (int c0 = 0; c0 < Cn; c0 += 32) {
#pragma unroll
        for (int i = 0; i < 8; ++i) {
            int idx = tid + i * 256;
            int r = idx >> 5, kk = idx & 31;
            int gr = r0 + r;
            Xs[r * 33 + kk] = (gr < Kn) ? X[gr * Cn + c0 + kk] : 0.f;
            int gj = j0 + r;
            As[r * 33 + kk] = (gj < Kn) ? A2[gj * Cn + c0 + kk] : 0.f;
        }
        __syncthreads();
#pragma unroll
        for (int kk = 0; kk < 32; ++kk) {
            float a0 = Xs[(ty * 4 + 0) * 33 + kk];
            float a1 = Xs[(ty * 4 + 1) * 33 + kk];
            float a2 = Xs[(ty * 4 + 2) * 33 + kk];
            float a3 = Xs[(ty * 4 + 3) * 33 + kk];
            float b0 = As[(tx * 4 + 0) * 33 + kk];
            float b1 = As[(tx * 4 + 1) * 33 + kk];
            float b2 = As[(tx * 4 + 2) * 33 + kk];
            float b3 = As[(tx * 4 + 3) * 33 + kk];
            acc[0][0] += a0 * b0; acc[0][1] += a0 * b1; acc[0][2] += a0 * b2; acc[0][3] += a0 * b3;
            acc[1][0] += a1 * b0; acc[1][1] += a1 * b1; acc[1][2] += a1 * b2; acc[1][3] += a1 * b3;
            acc[2][0] += a2 * b0; acc[2][1] += a2 * b1; acc[2][2] += a2 * b2; acc[2][3] += a2 * b3;
            acc[3][0] += a3 * b0; acc[3][1] += a3 * b1; acc[3][2] += a3 * b2; acc[3][3] += a3 * b3;
        }
        __syncthreads();
    }
#pragma unroll
    for (int m = 0; m < 4; ++m) {
        int gr = r0 + ty * 4 + m;
        if (gr < Kn) {
#pragma unroll
            for (int n = 0; n < 4; ++n) {
                int gj = j0 + tx * 4 + n;
                if (gj < Kn) out[gr * Kn + gj] = acc[m][n];
            }
        }
    }
}

// ---------------------------------------------------------------------------
// K3: packed-lower-triangle Cholesky (M is SPD), NB=8, 2 barriers/step.
// Grid 1600 (non-persistent: R2's persistent variant measured -46us).
// LDS-pipe diet: f-reads 8xb32 -> 5xb64 (align-down + wave-uniform parity
// select); pv-reads same trick with per-lane select. The stray words read
// by the widened loads are provably unused (selected out), so no race with
// concurrent phase-T writes. tri[20104]: +4 floats overrun pad.
// ---------------------------------------------------------------------------
template<int QQ>
__device__ __forceinline__ void back_range_chol(float y[4], const float* tri,
                                                int lane, int khi, int klo,
                                                int& offk)
{
    for (int k = khi; k >= klo; --k) {
        float dinv = tri[offk + k];                 // 1/L[k][k] (broadcast)
        float xk = __shfl(y[QQ], k & 63) * dinv;
        if (lane == (k & 63)) y[QQ] = xk;
#pragma unroll
        for (int q2 = 0; q2 <= QQ; ++q2) {
            int r = lane + 64 * q2;
            if (r < k) y[q2] -= tri[offk + r] * xk; // L[k][r], row k packed
        }
        offk -= k;                                  // off(k-1) = off(k) - k
    }
}

__global__ __launch_bounds__(512, 4) void k_solve(
    const float* __restrict__ AAT,
    const float* __restrict__ evalx, const float* __restrict__ evaly,
    const float* __restrict__ graw, const float* __restrict__ lraw,
    float* __restrict__ out)
{
    __shared__ float tri[20104];   // packed lower triangle, row r at r(r+1)/2
    __shared__ float rhs[200];
    __shared__ float sAux[8];
    const int bid = blockIdx.x;
    const int b = bid / 200;
    const int i = bid - b * 200;
    const int tid = threadIdx.x;
    const int w = tid >> 6, l = tid & 63;
    const float* __restrict__ Sb = AAT + b * 40000;
    const float* __restrict__ Rb = AAT + 320000 + bid * 200;
    const float* __restrict__ ex = evalx + b * Kn;
    const float* __restrict__ ey = evaly + b * Kn;

    // load lower triangle of S (coalesced per row) + rhs
    for (int r = w; r < 200; r += 8) {
        int off = r * (r + 1) / 2;
        for (int c = l; c <= r; c += 64) tri[off + c] = Sb[r * 200 + c];
    }
    if (tid < 200) rhs[tid] = Rb[tid];

    // scaling = max(max ex, max ey) over the batch (wave 0)
    if (tid < 64) {
        float mx = 0.f;
        for (int j = tid; j < 200; j += 64) mx = fmaxf(mx, fmaxf(ex[j], ey[j]));
#pragma unroll
        for (int s = 32; s > 0; s >>= 1) mx = fmaxf(mx, __shfl_down(mx, s));
        if (tid == 0) sAux[0] = mx;
    }
    __syncthreads();

    // diagonal: += lambda * D[b,i,r]
    if (tid < 200) {
        int r = tid;
        float s = sAux[0];
        float g = 1.f / (1.f + expf(-graw[0]));
        float lr = lraw[0];
        float sp = fmaxf(lr, 0.f) + log1pf(expf(-fabsf(lr)));   // stable softplus
        float lmb = 10.f + sp * (990.f / 1000.f);
        lmb = fminf(fmaxf(lmb, 10.f), 1000.f);
        float gx = powf(ex[i] / s, g);
        float gy = powf(ey[r] / s, g);
        float d1 = 1.f / (gx * gx + 1.f);
        float d2 = 1.f / (gy * gy + 1.f);
        float re = gy * d2 - gx * d1;
        float im = d2 - d1;
        tri[r * (r + 1) / 2 + r] += lmb * (re * re + im * im);
    }
    __syncthreads();

    // blocked Cholesky, NB = 8, 25 steps, 2 barriers/step
    for (int k = 0; k < 200; k += 8) {
        // ---- phase P: wave 0 factors panel + fused forward-solve on rhs
        if (tid < 64) {
            float p[4][9];
#pragma unroll
            for (int q = 0; q < 4; ++q) {
                int r = k + l + 64 * q;
                if (r < 200) {
                    int off = r * (r + 1) / 2;
#pragma unroll
                    for (int c = 0; c < 8; ++c)
                        p[q][c] = (k + c <= r) ? tri[off + k + c] : 0.f;
                    p[q][8] = rhs[r];
                } else {
#pragma unroll
                    for (int c = 0; c < 9; ++c) p[q][c] = 0.f;
                }
            }
#pragma unroll
            for (int c = 0; c < 8; ++c) {
                float d = __shfl(p[0][c], c);        // pivot row k+c = lane c
                float s = 1.0f / sqrtf(d);
#pragma unroll
                for (int q = 0; q < 4; ++q) {
                    bool act = (q > 0) || (l > c);
                    if (act) p[q][c] *= s;
                }
                if (l == c) p[0][c] = s;             // store 1/L[k][k] on diag
                float Lj[8];
#pragma unroll
                for (int j = c + 1; j < 8; ++j) Lj[j] = __shfl(p[0][c], j);
                float yc = __shfl(p[0][8], c) * s;
                if (l == c) p[0][8] = yc;
#pragma unroll
                for (int q = 0; q < 4; ++q) {
                    bool act = (q > 0) || (l > c);
                    if (act) {
                        float Lrc = p[q][c];
#pragma unroll
                        for (int j = c + 1; j < 8; ++j) p[q][j] -= Lrc * Lj[j];
                        p[q][8] -= Lrc * yc;
                    }
                }
            }
#pragma unroll
            for (int q = 0; q < 4; ++q) {
                int r = k + l + 64 * q;
                if (r < 200) {
                    int off = r * (r + 1) / 2;
#pragma unroll
                    for (int c = 0; c < 8; ++c)
                        if (k + c <= r) tri[off + k + c] = p[q][c];
                    rhs[r] = p[q][8];
                }
            }
        }
        __syncthreads();

        // ---- phase T: symmetric rank-8 trailing update of lower triangle
        {
            const int jb0 = k + 8;
            if (jb0 < 200) {
                // pv: panel rows j (lane-distinct), cols k..k+7, via 5x b64
                float pv[4][8];
#pragma unroll
                for (int ch = 0; ch < 4; ++ch) {
                    int j = jb0 + ch * 64 + l;
                    if (j < 200) {
                        int base = j * (j + 1) / 2 + k;
                        int sj = base & 1;
                        const float2* p2 = (const float2*)&tri[base - sj];
                        float bf[10];
#pragma unroll
                        for (int u = 0; u < 5; ++u) {
                            float2 v = p2[u]; bf[2 * u] = v.x; bf[2 * u + 1] = v.y;
                        }
#pragma unroll
                        for (int c = 0; c < 8; ++c)
                            pv[ch][c] = sj ? bf[c + 1] : bf[c];
                    }
                }
                for (int r = jb0 + w; r < 200; r += 8) {
                    int offr = r * (r + 1) / 2;
                    // f: broadcast read of row r cols k..k+7, via 5x b64
                    int fb = offr + k;
                    int fs = fb & 1;                 // wave-uniform
                    const float2* f2 = (const float2*)&tri[fb - fs];
                    float fbuf[10];
#pragma unroll
                    for (int u = 0; u < 5; ++u) {
                        float2 v = f2[u]; fbuf[2 * u] = v.x; fbuf[2 * u + 1] = v.y;
                    }
                    float f[8];
#pragma unroll
                    for (int c = 0; c < 8; ++c)
                        f[c] = fs ? fbuf[c + 1] : fbuf[c];
#pragma unroll
                    for (int ch = 0; ch < 4; ++ch) {
                        int j = jb0 + ch * 64 + l;
                        if (j <= r) {
                            float a = tri[offr + j];    // stride-1 across lanes
#pragma unroll
                            for (int c = 0; c < 8; ++c) a -= f[c] * pv[ch][c];
                            tri[offr + j] = a;
                        }
                    }
                }
            }
        }
        __syncthreads();
    }

    // back-substitution with L^T on wave 0
    if (tid < 64) {
        float y[4];
#pragma unroll
        for (int q = 0; q < 4; ++q) {
            int r = l + 64 * q;
            y[q] = (r < 200) ? rhs[r] : 0.f;
        }
        int offk = 19900;                     // off(199)
        back_range_chol<3>(y, tri, l, 199, 192, offk);
        back_range_chol<2>(y, tri, l, 191, 128, offk);
        back_range_chol<1>(y, tri, l, 127, 64, offk);
        back_range_chol<0>(y, tri, l, 63, 0, offk);
#pragma unroll
        for (int q = 0; q < 4; ++q) {
            int r = l + 64 * q;
            if (r < 200) out[bid * 200 + r] = y[q];
        }
    }
}

// ---------------------------------------------------------------------------
extern "C" void kernel_launch(void* const* d_in, const int* in_sizes, int n_in,
                              void* d_out, int out_size, void* d_ws, size_t ws_size,
                              hipStream_t stream)
{
    const float* fx   = (const float*)d_in[0];   // feat_x   [8,5000,256]
    const float* fy   = (const float*)d_in[1];   // feat_y
    const float* evx  = (const float*)d_in[2];   // evals_x  [8,200]
    const float* evy  = (const float*)d_in[3];   // evals_y
    const float* etx  = (const float*)d_in[4];   // evecs_trans_x [8,200,5000]
    const float* ety  = (const float*)d_in[5];   // evecs_trans_y
    const float* graw = (const float*)d_in[6];   // gamma_raw scalar
    const float* lraw = (const float*)d_in[7];   // lambda_raw scalar
    float* out = (float*)d_out;
    float* ws  = (float*)d_ws;

    const bool use_part = ws_size >= WS_NEED_FLOATS * sizeof(float);
    if (use_part) {
        k_gemm_ab<0><<<dim3(2048), dim3(128), 0, stream>>>(
            fx, fy, etx, ety, ws + AB_OFF, ws + PART_OFF);
        k_reduce<<<dim3(400), dim3(512), 0, stream>>>(
            (const float4*)(ws + PART_OFF), (float4*)(ws + AB_OFF));
    } else {
        hipMemsetAsync(ws + AB_OFF, 0, (size_t)16 * Kn * Cn * sizeof(float), stream);
        k_gemm_ab<1><<<dim3(2048), dim3(128), 0, stream>>>(
            fx, fy, etx, ety, ws + AB_OFF, ws + AB_OFF /*unused*/);
    }
    k_gemm_nt<<<dim3(256), dim3(256), 0, stream>>>(ws + AB_OFF, ws + AAT_OFF);
    k_solve<<<dim3(1600), dim3(512), 0, stream>>>(
        ws + AAT_OFF, evx, evy, graw, lraw, out);
}

// Round 4
// 991.116 us; speedup vs baseline: 3.3466x; 3.3466x over previous
//
#include <hip/hip_runtime.h>
#include <math.h>

#define Bn 8
#define Vn 5000
#define Cn 256
#define Kn 200

// workspace layout (floats):
//   AB   [16][200][256] @ 0         (mats 0..7 = A per batch, 8..15 = Bc)
//   AAT  [16][200][200] @ 819200    (mats 0..7 = A·Aᵀ, 8..15 = B·Aᵀ)
//   PART [8][16][200][256] @ 1459456 (split-K partials, if ws is big enough)
#define AB_OFF   0
#define AAT_OFF  819200
#define PART_OFF 1459456
#define WS_NEED_FLOATS (PART_OFF + (size_t)8 * 16 * Kn * Cn)

// ---------------------------------------------------------------------------
// K1: A[b] = evecs_trans_x[b] (200x5000) @ feat_x[b] (5000x256), same for y.
// R2 config exactly (measured ~280us within R2 total): tile 64x128, 128 thr,
// 8x8 micro, 4 ds_read_b128 per 64 FMAs, split-K=8, partials (no atomics).
// NOTE: do NOT add a min-waves clause to launch_bounds -- R3's (128,4)
// capped VGPRs at 128 (acc alone is 64) and spilled, 3x regression.
// ---------------------------------------------------------------------------
template<int USE_ATOMIC>
__global__ __launch_bounds__(128) void k_gemm_ab(
    const float* __restrict__ fx, const float* __restrict__ fy,
    const float* __restrict__ etx, const float* __restrict__ ety,
    float* __restrict__ AB, float* __restrict__ part)
{
    __shared__ float EsT[16 * 72];    // [kk][row]
    __shared__ float Fs[16 * 132];    // [kk][col]
    const int bid = blockIdx.x;       // 16 mats * 4 tr * 2 tc * 8 ks = 1024
    const int ks  = bid & 7;
    const int t   = bid >> 3;         // mat*8 + tr*2 + tc
    const int tc  = t & 1;
    const int tr  = (t >> 1) & 3;
    const int mat = t >> 3;
    const int b = mat & 7, which = mat >> 3;
    const float* __restrict__ E = (which ? ety : etx) + (size_t)b * Kn * Vn;
    const float* __restrict__ F = (which ? fy : fx) + (size_t)b * Vn * Cn;
    const int row0 = tr * 64, col0 = tc * 128;
    const int kstart = ks * 640;
    const int kend = (kstart + 640 < Vn) ? (kstart + 640) : Vn;
    const int tid = threadIdx.x;
    const int tx = tid & 15, ty = tid >> 4;   // cols 16x8, rows 8x8
    float4 acc[8][2] = {};

    for (int k0 = kstart; k0 < kend; k0 += 16) {
#pragma unroll
        for (int i = 0; i < 2; ++i) {
            int idx = tid + i * 128;          // 256 float4s
            int r = idx >> 2, k4 = idx & 3;
            int gr = row0 + r, gk = k0 + k4 * 4;
            float4 v = make_float4(0.f, 0.f, 0.f, 0.f);
            if (gr < Kn && gk < kend) v = *(const float4*)&E[(size_t)gr * Vn + gk];
            EsT[(k4 * 4 + 0) * 72 + r] = v.x;
            EsT[(k4 * 4 + 1) * 72 + r] = v.y;
            EsT[(k4 * 4 + 2) * 72 + r] = v.z;
            EsT[(k4 * 4 + 3) * 72 + r] = v.w;
        }
#pragma unroll
        for (int i = 0; i < 4; ++i) {
            int idx = tid + i * 128;          // 512 float4s
            int c4 = idx & 31, rv = idx >> 5;
            int gv = k0 + rv;
            float4 v = make_float4(0.f, 0.f, 0.f, 0.f);
            if (gv < kend) v = *(const float4*)&F[(size_t)gv * Cn + col0 + c4 * 4];
            *(float4*)&Fs[rv * 132 + c4 * 4] = v;
        }
        __syncthreads();
#pragma unroll
        for (int kk = 0; kk < 16; ++kk) {
            float4 a0 = *(const float4*)&EsT[kk * 72 + ty * 8];
            float4 a1 = *(const float4*)&EsT[kk * 72 + ty * 8 + 4];
            float4 b0 = *(const float4*)&Fs[kk * 132 + tx * 8];
            float4 b1 = *(const float4*)&Fs[kk * 132 + tx * 8 + 4];
            float av[8] = {a0.x, a0.y, a0.z, a0.w, a1.x, a1.y, a1.z, a1.w};
#pragma unroll
            for (int m = 0; m < 8; ++m) {
                acc[m][0].x += av[m] * b0.x; acc[m][0].y += av[m] * b0.y;
                acc[m][0].z += av[m] * b0.z; acc[m][0].w += av[m] * b0.w;
                acc[m][1].x += av[m] * b1.x; acc[m][1].y += av[m] * b1.y;
                acc[m][1].z += av[m] * b1.z; acc[m][1].w += av[m] * b1.w;
            }
        }
        __syncthreads();
    }

#pragma unroll
    for (int m = 0; m < 8; ++m) {
        int gr = row0 + ty * 8 + m;
        if (gr < Kn) {
            if (USE_ATOMIC) {
                float* o = AB + ((size_t)mat * Kn + gr) * Cn + col0 + tx * 8;
                atomicAdd(&o[0], acc[m][0].x); atomicAdd(&o[1], acc[m][0].y);
                atomicAdd(&o[2], acc[m][0].z); atomicAdd(&o[3], acc[m][0].w);
                atomicAdd(&o[4], acc[m][1].x); atomicAdd(&o[5], acc[m][1].y);
                atomicAdd(&o[6], acc[m][1].z); atomicAdd(&o[7], acc[m][1].w);
            } else {
                float* o = part + (((size_t)(ks * 16 + mat) * Kn + gr) * Cn) + col0 + tx * 8;
                *(float4*)&o[0] = acc[m][0];
                *(float4*)&o[4] = acc[m][1];
            }
        }
    }
}

// ---------------------------------------------------------------------------
// K1b: AB = sum over 8 split-K partials. ~30 MB traffic, ~6us.
// ---------------------------------------------------------------------------
__global__ __launch_bounds__(512) void k_reduce(
    const float4* __restrict__ part, float4* __restrict__ AB)
{
    const int i = blockIdx.x * 512 + threadIdx.x;   // 204800 float4s, grid 400
    float4 s = part[i];
#pragma unroll
    for (int sp = 1; sp < 8; ++sp) {
        float4 v = part[(size_t)sp * 204800 + i];
        s.x += v.x; s.y += v.y; s.z += v.z; s.w += v.w;
    }
    AB[i] = s;
}

// ---------------------------------------------------------------------------
// K2: AAT[m] = X[m] (200x256) @ A2ᵀ (256x200), X = A (m<8) or Bc (m>=8).
// ---------------------------------------------------------------------------
__global__ __launch_bounds__(256) void k_gemm_nt(
    const float* __restrict__ AB, float* __restrict__ AAT)
{
    __shared__ float Xs[64 * 33];
    __shared__ float As[64 * 33];
    const int bid = blockIdx.x;
    const int mat = bid >> 4;
    const int tile = bid & 15;
    const int tr = tile >> 2, tc = tile & 3;
    const float* __restrict__ X  = AB + mat * Kn * Cn;
    const float* __restrict__ A2 = AB + (mat & 7) * Kn * Cn;
    float* __restrict__ out = AAT + mat * Kn * Kn;
    const int r0 = tr * 64, j0 = tc * 64;
    const int tid = threadIdx.x;
    const int tx = tid & 15, ty = tid >> 4;
    float acc[4][4] = {};

    for (int c0 = 0; c0 < Cn; c0 += 32) {
#pragma unroll
        for (int i = 0; i < 8; ++i) {
            int idx = tid + i * 256;
            int r = idx >> 5, kk = idx & 31;
            int gr = r0 + r;
            Xs[r * 33 + kk] = (gr < Kn) ? X[gr * Cn + c0 + kk] : 0.f;
            int gj = j0 + r;
            As[r * 33 + kk] = (gj < Kn) ? A2[gj * Cn + c0 + kk] : 0.f;
        }
        __syncthreads();
#pragma unroll
        for (int kk = 0; kk < 32; ++kk) {
            float a0 = Xs[(ty * 4 + 0) * 33 + kk];
            float a1 = Xs[(ty * 4 + 1) * 33 + kk];
            float a2 = Xs[(ty * 4 + 2) * 33 + kk];
            float a3 = Xs[(ty * 4 + 3) * 33 + kk];
            float b0 = As[(tx * 4 + 0) * 33 + kk];
            float b1 = As[(tx * 4 + 1) * 33 + kk];
            float b2 = As[(tx * 4 + 2) * 33 + kk];
            float b3 = As[(tx * 4 + 3) * 33 + kk];
            acc[0][0] += a0 * b0; acc[0][1] += a0 * b1; acc[0][2] += a0 * b2; acc[0][3] += a0 * b3;
            acc[1][0] += a1 * b0; acc[1][1] += a1 * b1; acc[1][2] += a1 * b2; acc[1][3] += a1 * b3;
            acc[2][0] += a2 * b0; acc[2][1] += a2 * b1; acc[2][2] += a2 * b2; acc[2][3] += a2 * b3;
            acc[3][0] += a3 * b0; acc[3][1] += a3 * b1; acc[3][2] += a3 * b2; acc[3][3] += a3 * b3;
        }
        __syncthreads();
    }
#pragma unroll
    for (int m = 0; m < 4; ++m) {
        int gr = r0 + ty * 4 + m;
        if (gr < Kn) {
#pragma unroll
            for (int n = 0; n < 4; ++n) {
                int gj = j0 + tx * 4 + n;
                if (gj < Kn) out[gr * Kn + gj] = acc[m][n];
            }
        }
    }
}

// ---------------------------------------------------------------------------
// K3: packed-lower-triangle Cholesky (M is SPD), NB=8, 2 barriers/step.
// R1 version exactly (measured 660us): grid 1600 non-persistent, scalar
// phase-T accesses. Do NOT hand-widen LDS reads (R3: 3.3x regression) and
// do NOT convert to persistent blocks (R2: +46us).
// ---------------------------------------------------------------------------
template<int QQ>
__device__ __forceinline__ void back_range_chol(float y[4], const float* tri,
                                                int lane, int khi, int klo,
                                                int& offk)
{
    for (int k = khi; k >= klo; --k) {
        float dinv = tri[offk + k];                 // 1/L[k][k] (broadcast)
        float xk = __shfl(y[QQ], k & 63) * dinv;
        if (lane == (k & 63)) y[QQ] = xk;
#pragma unroll
        for (int q2 = 0; q2 <= QQ; ++q2) {
            int r = lane + 64 * q2;
            if (r < k) y[q2] -= tri[offk + r] * xk; // L[k][r], row k packed
        }
        offk -= k;                                  // off(k-1) = off(k) - k
    }
}

__global__ __launch_bounds__(512, 4) void k_solve(
    const float* __restrict__ AAT,
    const float* __restrict__ evalx, const float* __restrict__ evaly,
    const float* __restrict__ graw, const float* __restrict__ lraw,
    float* __restrict__ out)
{
    __shared__ float tri[20100];   // packed lower triangle, row r at r(r+1)/2
    __shared__ float rhs[200];
    __shared__ float sAux[8];
    const int bid = blockIdx.x;
    const int b = bid / 200;
    const int i = bid - b * 200;
    const int tid = threadIdx.x;
    const int w = tid >> 6, l = tid & 63;
    const float* __restrict__ Sb = AAT + b * 40000;
    const float* __restrict__ Rb = AAT + 320000 + bid * 200;
    const float* __restrict__ ex = evalx + b * Kn;
    const float* __restrict__ ey = evaly + b * Kn;

    // load lower triangle of S (coalesced per row) + rhs
    for (int r = w; r < 200; r += 8) {
        int off = r * (r + 1) / 2;
        for (int c = l; c <= r; c += 64) tri[off + c] = Sb[r * 200 + c];
    }
    if (tid < 200) rhs[tid] = Rb[tid];

    // scaling = max(max ex, max ey) over the batch (wave 0)
    if (tid < 64) {
        float mx = 0.f;
        for (int j = tid; j < 200; j += 64) mx = fmaxf(mx, fmaxf(ex[j], ey[j]));
#pragma unroll
        for (int s = 32; s > 0; s >>= 1) mx = fmaxf(mx, __shfl_down(mx, s));
        if (tid == 0) sAux[0] = mx;
    }
    __syncthreads();

    // diagonal: += lambda * D[b,i,r]
    if (tid < 200) {
        int r = tid;
        float s = sAux[0];
        float g = 1.f / (1.f + expf(-graw[0]));
        float lr = lraw[0];
        float sp = fmaxf(lr, 0.f) + log1pf(expf(-fabsf(lr)));   // stable softplus
        float lmb = 10.f + sp * (990.f / 1000.f);
        lmb = fminf(fmaxf(lmb, 10.f), 1000.f);
        float gx = powf(ex[i] / s, g);
        float gy = powf(ey[r] / s, g);
        float d1 = 1.f / (gx * gx + 1.f);
        float d2 = 1.f / (gy * gy + 1.f);
        float re = gy * d2 - gx * d1;
        float im = d2 - d1;
        tri[r * (r + 1) / 2 + r] += lmb * (re * re + im * im);
    }
    __syncthreads();

    // blocked Cholesky, NB = 8, 25 steps, 2 barriers/step
    for (int k = 0; k < 200; k += 8) {
        // ---- phase P: wave 0 factors panel + fused forward-solve on rhs
        if (tid < 64) {
            float p[4][9];
#pragma unroll
            for (int q = 0; q < 4; ++q) {
                int r = k + l + 64 * q;
                if (r < 200) {
                    int off = r * (r + 1) / 2;
#pragma unroll
                    for (int c = 0; c < 8; ++c)
                        p[q][c] = (k + c <= r) ? tri[off + k + c] : 0.f;
                    p[q][8] = rhs[r];
                } else {
#pragma unroll
                    for (int c = 0; c < 9; ++c) p[q][c] = 0.f;
                }
            }
#pragma unroll
            for (int c = 0; c < 8; ++c) {
                float d = __shfl(p[0][c], c);        // pivot row k+c = lane c
                float s = 1.0f / sqrtf(d);
#pragma unroll
                for (int q = 0; q < 4; ++q) {
                    bool act = (q > 0) || (l > c);
                    if (act) p[q][c] *= s;
                }
                if (l == c) p[0][c] = s;             // store 1/L[k][k] on diag
                float Lj[8];
#pragma unroll
                for (int j = c + 1; j < 8; ++j) Lj[j] = __shfl(p[0][c], j);
                float yc = __shfl(p[0][8], c) * s;
                if (l == c) p[0][8] = yc;
#pragma unroll
                for (int q = 0; q < 4; ++q) {
                    bool act = (q > 0) || (l > c);
                    if (act) {
                        float Lrc = p[q][c];
#pragma unroll
                        for (int j = c + 1; j < 8; ++j) p[q][j] -= Lrc * Lj[j];
                        p[q][8] -= Lrc * yc;
                    }
                }
            }
#pragma unroll
            for (int q = 0; q < 4; ++q) {
                int r = k + l + 64 * q;
                if (r < 200) {
                    int off = r * (r + 1) / 2;
#pragma unroll
                    for (int c = 0; c < 8; ++c)
                        if (k + c <= r) tri[off + k + c] = p[q][c];
                    rhs[r] = p[q][8];
                }
            }
        }
        __syncthreads();

        // ---- phase T: symmetric rank-8 trailing update of lower triangle
        {
            const int jb0 = k + 8;
            if (jb0 < 200) {
                float pv[4][8];
#pragma unroll
                for (int ch = 0; ch < 4; ++ch) {
                    int j = jb0 + ch * 64 + l;
                    if (j < 200) {
                        int offj = j * (j + 1) / 2;
#pragma unroll
                        for (int c = 0; c < 8; ++c) pv[ch][c] = tri[offj + k + c];
                    }
                }
                for (int r = jb0 + w; r < 200; r += 8) {
                    int offr = r * (r + 1) / 2;
                    float f[8];
#pragma unroll
                    for (int c = 0; c < 8; ++c) f[c] = tri[offr + k + c]; // bcast
#pragma unroll
                    for (int ch = 0; ch < 4; ++ch) {
                        int j = jb0 + ch * 64 + l;
                        if (j <= r) {
                            float a = tri[offr + j];    // stride-1 across lanes
#pragma unroll
                            for (int c = 0; c < 8; ++c) a -= f[c] * pv[ch][c];
                            tri[offr + j] = a;
                        }
                    }
                }
            }
        }
        __syncthreads();
    }

    // back-substitution with L^T on wave 0
    if (tid < 64) {
        float y[4];
#pragma unroll
        for (int q = 0; q < 4; ++q) {
            int r = l + 64 * q;
            y[q] = (r < 200) ? rhs[r] : 0.f;
        }
        int offk = 19900;                     // off(199)
        back_range_chol<3>(y, tri, l, 199, 192, offk);
        back_range_chol<2>(y, tri, l, 191, 128, offk);
        back_range_chol<1>(y, tri, l, 127, 64, offk);
        back_range_chol<0>(y, tri, l, 63, 0, offk);
#pragma unroll
        for (int q = 0; q < 4; ++q) {
            int r = l + 64 * q;
            if (r < 200) out[bid * 200 + r] = y[q];
        }
    }
}

// ---------------------------------------------------------------------------
extern "C" void kernel_launch(void* const* d_in, const int* in_sizes, int n_in,
                              void* d_out, int out_size, void* d_ws, size_t ws_size,
                              hipStream_t stream)
{
    const float* fx   = (const float*)d_in[0];   // feat_x   [8,5000,256]
    const float* fy   = (const float*)d_in[1];   // feat_y
    const float* evx  = (const float*)d_in[2];   // evals_x  [8,200]
    const float* evy  = (const float*)d_in[3];   // evals_y
    const float* etx  = (const float*)d_in[4];   // evecs_trans_x [8,200,5000]
    const float* ety  = (const float*)d_in[5];   // evecs_trans_y
    const float* graw = (const float*)d_in[6];   // gamma_raw scalar
    const float* lraw = (const float*)d_in[7];   // lambda_raw scalar
    float* out = (float*)d_out;
    float* ws  = (float*)d_ws;

    const bool use_part = ws_size >= WS_NEED_FLOATS * sizeof(float);
    if (use_part) {
        k_gemm_ab<0><<<dim3(1024), dim3(128), 0, stream>>>(
            fx, fy, etx, ety, ws + AB_OFF, ws + PART_OFF);
        k_reduce<<<dim3(400), dim3(512), 0, stream>>>(
            (const float4*)(ws + PART_OFF), (float4*)(ws + AB_OFF));
    } else {
        hipMemsetAsync(ws + AB_OFF, 0, (size_t)16 * Kn * Cn * sizeof(float), stream);
        k_gemm_ab<1><<<dim3(1024), dim3(128), 0, stream>>>(
            fx, fy, etx, ety, ws + AB_OFF, ws + AB_OFF /*unused*/);
    }
    k_gemm_nt<<<dim3(256), dim3(256), 0, stream>>>(ws + AB_OFF, ws + AAT_OFF);
    k_solve<<<dim3(1600), dim3(512), 0, stream>>>(
        ws + AAT_OFF, evx, evy, graw, lraw, out);
}